// Round 1
// baseline (966.626 us; speedup 1.0000x reference)
//
#include <hip/hip_runtime.h>
#include <cstdint>
#include <cstddef>

typedef __attribute__((ext_vector_type(8))) short short8;
typedef __attribute__((ext_vector_type(4))) short short4v;
typedef __attribute__((ext_vector_type(4))) float float4v;
typedef __attribute__((ext_vector_type(4))) int int4v;
typedef unsigned short ushort_t;

__device__ __forceinline__ ushort_t f2bf(float f) {
  unsigned u = __builtin_bit_cast(unsigned, f);
  u = (u + 0x7FFFu + ((u >> 16) & 1u)) >> 16;  // RNE
  return (ushort_t)u;
}
__device__ __forceinline__ float bf2f(ushort_t h) {
  unsigned u = ((unsigned)h) << 16;
  return __builtin_bit_cast(float, u);
}

__device__ __forceinline__ void gld_lds16(const void* g, void* l) {
  __builtin_amdgcn_global_load_lds(
      (const __attribute__((address_space(1))) void*)g,
      (__attribute__((address_space(3))) void*)l, 16, 0, 0);
}

// ---------------------------------------------------------------------------
// TN GEMM: C[m][n] = sum_k A[m][k] * B[n][k], A:[M][K] bf16 row-major,
// B:[N][K] bf16 row-major, C partials fp32 [S][M][N]. Tile 128x128, BK=64.
// grid = (M/128, N/128, S), block = 256 (4 waves, 2x2 wave grid of 64x64).
// ---------------------------------------------------------------------------
__global__ __launch_bounds__(256, 2) void gemm_tn(
    const ushort_t* __restrict__ A, const ushort_t* __restrict__ B,
    float* __restrict__ P, int M, int N, int K, int kslice) {
  __shared__ ushort_t As[128 * 64];
  __shared__ ushort_t Bs[128 * 64];
  const int tid = threadIdx.x;
  const int lane = tid & 63;
  const int wave = tid >> 6;
  const int wm = (wave & 1) * 64;
  const int wn = (wave >> 1) * 64;
  const int m0 = blockIdx.x * 128;
  const int n0 = blockIdx.y * 128;
  const int k0 = blockIdx.z * kslice;
  float* __restrict__ Pc = P + (size_t)blockIdx.z * M * N;

  float4v acc[4][4] = {};

  for (int kt = 0; kt < kslice; kt += 64) {
    const ushort_t* Ag = A + (size_t)m0 * K + (k0 + kt);
    const ushort_t* Bg = B + (size_t)n0 * K + (k0 + kt);
#pragma unroll
    for (int i = 0; i < 4; i++) {
      int f = i * 4096 + tid * 16;  // flat byte in 16KB tile
      int r = f >> 7;               // row (128B per row = 64 bf16)
      int cb = f & 127;             // byte within row
      gld_lds16((const char*)(Ag + (size_t)r * K) + cb, (char*)As + f);
      gld_lds16((const char*)(Bg + (size_t)r * K) + cb, (char*)Bs + f);
    }
    __syncthreads();
#pragma unroll
    for (int ks = 0; ks < 64; ks += 32) {
      short8 af[4], bfr[4];
      const int kr = ks + (lane >> 4) * 8;
      const int l15 = lane & 15;
#pragma unroll
      for (int im = 0; im < 4; im++)
        af[im] = *(const short8*)&As[(wm + im * 16 + l15) * 64 + kr];
#pragma unroll
      for (int in = 0; in < 4; in++)
        bfr[in] = *(const short8*)&Bs[(wn + in * 16 + l15) * 64 + kr];
#pragma unroll
      for (int im = 0; im < 4; im++)
#pragma unroll
        for (int in = 0; in < 4; in++)
          acc[im][in] = __builtin_amdgcn_mfma_f32_16x16x32_bf16(
              af[im], bfr[in], acc[im][in], 0, 0, 0);
    }
    __syncthreads();
  }
  // C/D layout: col(n) = lane&15, row(m) = (lane>>4)*4 + reg  [m89/m91]
  const int cn = lane & 15;
  const int cr = (lane >> 4) * 4;
#pragma unroll
  for (int im = 0; im < 4; im++)
#pragma unroll
    for (int in = 0; in < 4; in++)
#pragma unroll
      for (int r = 0; r < 4; r++) {
        int m = wm + im * 16 + cr + r;
        int n = wn + in * 16 + cn;
        Pc[(size_t)(m0 + m) * N + (n0 + n)] = acc[im][in][r];
      }
}

// ---------------------------------------------------------------------------
// fp32 [R][C] -> bf16 transpose [C][R]; optionally also bf16 non-transposed.
// tile 64x64, 256 threads, 16 elems/thread.
// ---------------------------------------------------------------------------
__global__ __launch_bounds__(256) void dualcast_f32_k(
    const float* __restrict__ src, ushort_t* __restrict__ dstN,
    ushort_t* __restrict__ dstT, int R, int C) {
  __shared__ float tile[64][65];
  const int r0 = blockIdx.x * 64, c0 = blockIdx.y * 64;
  const int tr = threadIdx.x >> 2, cs = (threadIdx.x & 3) * 16;
  const float* s = src + (size_t)(r0 + tr) * C + c0 + cs;
  float v[16];
#pragma unroll
  for (int j = 0; j < 16; j += 4) {
    float4v t4 = *(const float4v*)(s + j);
    v[j] = t4.x; v[j + 1] = t4.y; v[j + 2] = t4.z; v[j + 3] = t4.w;
  }
#pragma unroll
  for (int j = 0; j < 16; j++) tile[tr][cs + j] = v[j];
  if (dstN) {
    short8 o[2];
#pragma unroll
    for (int j = 0; j < 16; j++) ((ushort_t*)o)[j] = f2bf(v[j]);
    ushort_t* d = dstN + (size_t)(r0 + tr) * C + c0 + cs;
    *(short8*)d = o[0];
    *(short8*)(d + 8) = o[1];
  }
  __syncthreads();
  const int tc = threadIdx.x >> 2, rs = (threadIdx.x & 3) * 16;
  short8 o[2];
#pragma unroll
  for (int j = 0; j < 16; j++) ((ushort_t*)o)[j] = f2bf(tile[rs + j][tc]);
  ushort_t* d = dstT + (size_t)(c0 + tc) * R + r0 + rs;
  *(short8*)d = o[0];
  *(short8*)(d + 8) = o[1];
}

// int32 [R][C] -> bf16 (x>0 ? 1 : 0) transposed [C][R]
__global__ __launch_bounds__(256) void tcast_i32_k(
    const int* __restrict__ src, ushort_t* __restrict__ dstT, int R, int C) {
  __shared__ float tile[64][65];
  const int r0 = blockIdx.x * 64, c0 = blockIdx.y * 64;
  const int tr = threadIdx.x >> 2, cs = (threadIdx.x & 3) * 16;
  const int* s = src + (size_t)(r0 + tr) * C + c0 + cs;
#pragma unroll
  for (int j = 0; j < 16; j += 4) {
    int4v t4 = *(const int4v*)(s + j);
    tile[tr][cs + j] = t4.x > 0 ? 1.f : 0.f;
    tile[tr][cs + j + 1] = t4.y > 0 ? 1.f : 0.f;
    tile[tr][cs + j + 2] = t4.z > 0 ? 1.f : 0.f;
    tile[tr][cs + j + 3] = t4.w > 0 ? 1.f : 0.f;
  }
  __syncthreads();
  const int tc = threadIdx.x >> 2, rs = (threadIdx.x & 3) * 16;
  short8 o[2];
#pragma unroll
  for (int j = 0; j < 16; j++) ((ushort_t*)o)[j] = f2bf(tile[rs + j][tc]);
  ushort_t* d = dstT + (size_t)(c0 + tc) * R + r0 + rs;
  *(short8*)d = o[0];
  *(short8*)(d + 8) = o[1];
}

// bf16 [R][C] -> bf16 transposed [C][R]
__global__ __launch_bounds__(256) void transpose_bf16_k(
    const ushort_t* __restrict__ src, ushort_t* __restrict__ dst, int R, int C) {
  __shared__ ushort_t tile[64][66];
  const int r0 = blockIdx.x * 64, c0 = blockIdx.y * 64;
  const int tr = threadIdx.x >> 2, cs = (threadIdx.x & 3) * 16;
  const ushort_t* s = src + (size_t)(r0 + tr) * C + c0 + cs;
  short8 v0 = *(const short8*)s, v1 = *(const short8*)(s + 8);
#pragma unroll
  for (int j = 0; j < 8; j++) {
    tile[tr][cs + j] = ((ushort_t*)&v0)[j];
    tile[tr][cs + 8 + j] = ((ushort_t*)&v1)[j];
  }
  __syncthreads();
  const int tc = threadIdx.x >> 2, rs = (threadIdx.x & 3) * 16;
  short8 o[2];
#pragma unroll
  for (int j = 0; j < 16; j++) ((ushort_t*)o)[j] = tile[rs + j][tc];
  ushort_t* d = dst + (size_t)(c0 + tc) * R + r0 + rs;
  *(short8*)d = o[0];
  *(short8*)(d + 8) = o[1];
}

// counts[e] = sum of bf16 row e of hT [E][Nn]
__global__ __launch_bounds__(256) void counts_k(
    const ushort_t* __restrict__ hT, float* __restrict__ counts, int Nn) {
  const int e = blockIdx.x * 4 + (threadIdx.x >> 6);
  const int lane = threadIdx.x & 63;
  const ushort_t* row = hT + (size_t)e * Nn;
  float s = 0.f;
  for (int i = 0; i < Nn / 512; i++) {
    short8 v = *(const short8*)&row[i * 512 + lane * 8];
#pragma unroll
    for (int j = 0; j < 8; j++) s += bf2f(((ushort_t*)&v)[j]);
  }
#pragma unroll
  for (int off = 32; off > 0; off >>= 1) s += __shfl_down(s, off);
  if (lane == 0) counts[e] = s;
}

// out_bf16[i] = sum_s P[s][i]
__global__ __launch_bounds__(256) void reduce_bf16_k(
    const float* __restrict__ P, ushort_t* __restrict__ out, int MN, int S) {
  const int i = (blockIdx.x * 256 + threadIdx.x) * 4;
  if (i >= MN) return;
  float4v s = {0.f, 0.f, 0.f, 0.f};
  for (int sp = 0; sp < S; sp++) s += *(const float4v*)&P[(size_t)sp * MN + i];
  short4v o;
#pragma unroll
  for (int j = 0; j < 4; j++) ((ushort_t*)&o)[j] = f2bf(s[j]);
  *(short4v*)&out[i] = o;
}

// per-row: sum split-K partials [S][M][128], layernorm, write fp32 [M][128]
__global__ __launch_bounds__(256) void reduce_ln_k(
    const float* __restrict__ P, const float* __restrict__ gamma,
    const float* __restrict__ beta, float* __restrict__ xo, int MN) {
  const int m = blockIdx.x * 4 + (threadIdx.x >> 6);
  const int lane = threadIdx.x & 63;
  const float* base = P + (size_t)m * 128 + lane;
  float v0 = 0.f, v1 = 0.f;
  for (int sp = 0; sp < 8; sp++) {
    v0 += base[(size_t)sp * MN];
    v1 += base[(size_t)sp * MN + 64];
  }
  float s = v0 + v1, sq = v0 * v0 + v1 * v1;
#pragma unroll
  for (int off = 32; off > 0; off >>= 1) {
    s += __shfl_down(s, off);
    sq += __shfl_down(sq, off);
  }
  s = __shfl(s, 0);
  sq = __shfl(sq, 0);
  const float mean = s * (1.f / 128.f);
  const float var = sq * (1.f / 128.f) - mean * mean;
  const float inv = rsqrtf(var + 1e-5f);
  xo[(size_t)m * 128 + lane] = (v0 - mean) * inv * gamma[lane] + beta[lane];
  xo[(size_t)m * 128 + lane + 64] =
      (v1 - mean) * inv * gamma[lane + 64] + beta[lane + 64];
}

// block b: reduce split partials of sums[e][d], divide by counts, partial max
__global__ __launch_bounds__(128) void mm1_k(
    const float* __restrict__ P, const float* __restrict__ counts,
    float* __restrict__ pm, int E, int D) {
  const int d = threadIdx.x;
  float vmax = -3.4e38f;
  const int e0 = blockIdx.x * 128;
  for (int e = e0; e < e0 + 128; e++) {
    float s = 0.f;
    for (int sp = 0; sp < 8; sp++)
      s += P[(size_t)sp * E * D + (size_t)e * D + d];
    vmax = fmaxf(vmax, s / counts[e]);
  }
  pm[blockIdx.x * 128 + d] = vmax;
}

__global__ __launch_bounds__(128) void mm2_k(
    const float* __restrict__ pm, float* __restrict__ out, int B) {
  const int d = threadIdx.x;
  float v = -3.4e38f;
  for (int b = 0; b < B; b++) v = fmaxf(v, pm[b * 128 + d]);
  out[d] = v;
}

// ---------------------------------------------------------------------------
extern "C" void kernel_launch(void* const* d_in, const int* in_sizes, int n_in,
                              void* d_out, int out_size, void* d_ws,
                              size_t ws_size, hipStream_t stream) {
  const float* x0 = (const float*)d_in[0];
  const float* T = (const float*)d_in[1];
  const float* gamma = (const float*)d_in[2];
  const float* beta = (const float*)d_in[3];
  const int* h = (const int*)d_in[4];
  float* out = (float*)d_out;

  const int N = 8192, E = 4096, D = 128, K = 8192, S = 8;

  char* ws = (char*)d_ws;
  size_t off = 0;
  auto alloc = [&](size_t bytes) {
    char* p = ws + off;
    off += (bytes + 255) & ~(size_t)255;
    return p;
  };
  ushort_t* Tb = (ushort_t*)alloc((size_t)N * N * 2);   // T bf16
  ushort_t* Tt = (ushort_t*)alloc((size_t)N * N * 2);   // T^T bf16
  ushort_t* hT = (ushort_t*)alloc((size_t)E * N * 2);   // h^T bf16
  ushort_t* xT = (ushort_t*)alloc((size_t)D * N * 2);   // x^T bf16
  ushort_t* tT = (ushort_t*)alloc((size_t)D * N * 2);   // t^T bf16
  ushort_t* trm = (ushort_t*)alloc((size_t)N * D * 2);  // t row-major bf16
  float* xlnf = (float*)alloc((size_t)N * D * 4);       // LN out fp32
  float* P = (float*)alloc((size_t)S * N * D * 4);      // split-K partials
  float* counts = (float*)alloc((size_t)E * 4);
  float* pm = (float*)alloc((size_t)32 * D * 4);
  (void)ws_size;

  // one pass over fp32 T produces both bf16 copies
  dualcast_f32_k<<<dim3(N / 64, N / 64), 256, 0, stream>>>(T, Tb, Tt, N, N);
  dualcast_f32_k<<<dim3(N / 64, D / 64), 256, 0, stream>>>(x0, nullptr, xT, N, D);
  tcast_i32_k<<<dim3(N / 64, E / 64), 256, 0, stream>>>(h, hT, N, E);
  counts_k<<<E / 4, 256, 0, stream>>>(hT, counts, N);

  for (int layer = 0; layer < 3; layer++) {
    // t = T @ x  (C[n][d] = sum_k T[n][k] * xT[d][k])
    gemm_tn<<<dim3(N / 128, D / 128, S), 256, 0, stream>>>(Tb, xT, P, N, D, K,
                                                           K / S);
    reduce_bf16_k<<<(N * D / 4 + 255) / 256, 256, 0, stream>>>(P, trm, N * D, S);
    transpose_bf16_k<<<dim3(N / 64, D / 64), 256, 0, stream>>>(trm, tT, N, D);
    // x' = T^T @ t  (C[m][d] = sum_k Tt[m][k] * tT[d][k])
    gemm_tn<<<dim3(N / 128, D / 128, S), 256, 0, stream>>>(Tt, tT, P, N, D, K,
                                                           K / S);
    reduce_ln_k<<<N / 4, 256, 0, stream>>>(P, gamma, beta, xlnf, N * D);
    dualcast_f32_k<<<dim3(N / 64, D / 64), 256, 0, stream>>>(xlnf, nullptr, xT,
                                                             N, D);
  }
  // sums[e][d] = sum_n hT[e][n] * xT[d][n]
  gemm_tn<<<dim3(E / 128, D / 128, S), 256, 0, stream>>>(hT, xT, P, E, D, K,
                                                         K / S);
  mm1_k<<<E / 128, 128, 0, stream>>>(P, counts, pm, E, D);
  mm2_k<<<1, 128, 0, stream>>>(pm, out, 32);
}